// Round 3
// baseline (333.520 us; speedup 1.0000x reference)
//
#include <hip/hip_runtime.h>
#include <hip/hip_bf16.h>
#include <stdint.h>

#define NB 8192
#define ND 1024
#define NC 14

// rotl via single v_alignbit_b32: ((x:x) >> (32-r)) == rotl(x, r)
#define ROTL(x, r) __builtin_amdgcn_alignbit((x), (x), 32u - (r))

// ---------------- host Threefry-2x32 (20 rounds), JAX-compatible ----------------
static inline uint32_t rotl32h(uint32_t x, int r) { return (x << r) | (x >> (32 - r)); }
static void tf2x32_host(uint32_t k0, uint32_t k1, uint32_t x0, uint32_t x1,
                        uint32_t* o0, uint32_t* o1) {
  uint32_t ks[3] = { k0, k1, k0 ^ k1 ^ 0x1BD11BDAu };
  static const int R[8] = {13, 15, 26, 6, 17, 29, 16, 24};
  x0 += k0; x1 += k1;
  for (int g = 0; g < 5; ++g) {
    const int* rr = (g & 1) ? (R + 4) : R;
    for (int i = 0; i < 4; ++i) { x0 += x1; x1 = rotl32h(x1, rr[i]); x1 ^= x0; }
    x0 += ks[(g + 1) % 3];
    x1 += ks[(g + 2) % 3] + (uint32_t)(g + 1);
  }
  *o0 = x0; *o1 = x1;
}

// ---------------- K1: row norms + label bitmasks (fused) ----------------
// lbits2[j] = labelmask | (bit14 if unlabeled). Then for ANY anchor i:
//   isPos(i,j) == (lbits2[i] & lbits2[j]) != 0
// (labeled i: bit14 of i is clear -> reduces to share; unlabeled i: mask is
//  exactly bit14 -> matches exactly the unlabeled j's.)
__global__ void k_norm(const float* __restrict__ pred, const float* __restrict__ gt,
                       float* __restrict__ norm, uint32_t* __restrict__ lbits2) {
  const int row = blockIdx.x;
  const float4* p = (const float4*)(pred + (size_t)row * ND);
  float4 v = p[threadIdx.x];
  float s = v.x * v.x + v.y * v.y + v.z * v.z + v.w * v.w;
#pragma unroll
  for (int o = 32; o > 0; o >>= 1) s += __shfl_down(s, o, 64);
  __shared__ float red[4];
  const int wave = threadIdx.x >> 6, lane = threadIdx.x & 63;
  if (lane == 0) red[wave] = s;
  unsigned long long b =
      __ballot((int)threadIdx.x < NC && gt[row * NC + (int)threadIdx.x] != 0.0f);
  __syncthreads();
  if (threadIdx.x == 0) {
    uint32_t m = (uint32_t)(b & 0x3FFFull);
    lbits2[row] = m | ((m == 0u) ? 0x4000u : 0u);
    norm[row] = sqrtf(red[0] + red[1] + red[2] + red[3]);
  }
}

// ---------------- K2: gumbel-argmax sampling (the heavy kernel) ----------------
__global__ void __launch_bounds__(256) k_sample(
    const uint32_t* __restrict__ lbits2,
    uint32_t kp0, uint32_t kp1, uint32_t kps2,
    uint32_t kn0, uint32_t kn1, uint32_t kns2,
    int* __restrict__ pos_idx, int* __restrict__ neg_idx) {
  const uint32_t tid = threadIdx.x;
  const int i = blockIdx.x;
  const uint32_t bi = lbits2[i];
  const uint32_t fbase = (uint32_t)i << 13;

  // Force key material into VGPRs ONCE (a VALU op may read at most 1 SGPR;
  // without this the compiler re-materializes v_movs inside the hot loop).
  uint32_t vkp0 = kp0, vkn0 = kn0, vkp1 = kp1, vkn1 = kn1;
  uint32_t vkps2 = kps2, vkns2 = kns2;
  uint32_t fkp1 = kp1 + fbase, fkn1 = kn1 + fbase;
  asm("" : "+v"(vkp0), "+v"(vkn0), "+v"(vkp1), "+v"(vkn1),
           "+v"(vkps2), "+v"(vkns2), "+v"(fkp1), "+v"(fkn1));

  uint32_t bkP = 0u, bjP = 0u, bkN = 0u, bjN = 0u;

#pragma unroll 8
  for (uint32_t k = 0; k < 32; ++k) {
    const uint32_t jv = tid + (k << 8);
    const uint32_t bj = lbits2[jv];
    const uint32_t m = bi & bj;            // != 0  <=>  positive
    const uint32_t s0 = m ? vkp0 : vkn0;   // 1 cmp reused by 4 cndmask
    const uint32_t s1 = m ? vkp1 : vkn1;
    const uint32_t s2 = m ? vkps2 : vkns2;
    const uint32_t f1 = m ? fkp1 : fkn1;
    uint32_t x0 = s0;
    uint32_t x1 = f1 + jv;                 // = K1 + (fbase + j)
#define TFR(r) { x0 += x1; x1 = ROTL(x1, r); x1 ^= x0; }
    TFR(13) TFR(15) TFR(26) TFR(6)
    x0 += s1;  x1 += s2 + 1u;
    TFR(17) TFR(29) TFR(16) TFR(24)
    x0 += s2;  x1 += s0 + 2u;
    TFR(13) TFR(15) TFR(26) TFR(6)
    x0 += s0;  x1 += s1 + 3u;
    TFR(17) TFR(29) TFR(16) TFR(24)
    x0 += s1;  x1 += s2 + 4u;
    TFR(13) TFR(15) TFR(26) TFR(6)
    x0 += s2;  x1 += s0 + 5u;
#undef TFR
    // +1 so a real candidate beats the 0-init; strict > keeps the first
    // (smallest-j) occurrence within a thread, matching jnp.argmax ties.
    const uint32_t key1 = ((x0 ^ x1) >> 9) + 1u;
    const bool pos = (m != 0u);
    const bool gtP = pos & (key1 > bkP);
    bkP = gtP ? key1 : bkP;
    bjP = gtP ? jv : bjP;
    const bool gtN = (!pos) & (key1 > bkN);
    bkN = gtN ? key1 : bkN;
    bjN = gtN ? jv : bjN;
  }

  // wave-level reduction with explicit (key, smaller-j) tie-break
#pragma unroll
  for (int off = 32; off > 0; off >>= 1) {
    uint32_t k2 = __shfl_down(bkP, off, 64), j2 = __shfl_down(bjP, off, 64);
    if (k2 > bkP || (k2 == bkP && j2 < bjP)) { bkP = k2; bjP = j2; }
    k2 = __shfl_down(bkN, off, 64); j2 = __shfl_down(bjN, off, 64);
    if (k2 > bkN || (k2 == bkN && j2 < bjN)) { bkN = k2; bjN = j2; }
  }
  __shared__ uint32_t sk[2][4], sj[2][4];
  const int wave = (int)tid >> 6, lane = (int)tid & 63;
  if (lane == 0) { sk[0][wave] = bkP; sj[0][wave] = bjP; sk[1][wave] = bkN; sj[1][wave] = bjN; }
  __syncthreads();
  if (tid == 0) {
    uint32_t bk = sk[0][0], bj = sj[0][0];
#pragma unroll
    for (int w = 1; w < 4; ++w)
      if (sk[0][w] > bk || (sk[0][w] == bk && sj[0][w] < bj)) { bk = sk[0][w]; bj = sj[0][w]; }
    pos_idx[i] = (bk == 0u) ? 0 : (int)bj;
    bk = sk[1][0]; bj = sj[1][0];
#pragma unroll
    for (int w = 1; w < 4; ++w)
      if (sk[1][w] > bk || (sk[1][w] == bk && sj[1][w] < bj)) { bk = sk[1][w]; bj = sj[1][w]; }
    neg_idx[i] = (bk == 0u) ? 0 : (int)bj;
  }
}

// ---------------- K3: per-row triplet cosine loss + atomic mean ----------------
__global__ void k_loss(const float* __restrict__ pred, const float* __restrict__ norm,
                       const int* __restrict__ pos_idx, const int* __restrict__ neg_idx,
                       float* __restrict__ out) {
  const int i = blockIdx.x;
  const int p = pos_idx[i];
  const int n = neg_idx[i];
  const float4* A = (const float4*)(pred + (size_t)i * ND);
  const float4* P = (const float4*)(pred + (size_t)p * ND);
  const float4* Nn = (const float4*)(pred + (size_t)n * ND);
  float4 a = A[threadIdx.x], pp = P[threadIdx.x], nn = Nn[threadIdx.x];
  float dp = a.x * pp.x + a.y * pp.y + a.z * pp.z + a.w * pp.w;
  float dn = a.x * nn.x + a.y * nn.y + a.z * nn.z + a.w * nn.w;
#pragma unroll
  for (int o = 32; o > 0; o >>= 1) {
    dp += __shfl_down(dp, o, 64);
    dn += __shfl_down(dn, o, 64);
  }
  __shared__ float rdp[4], rdn[4];
  int wave = threadIdx.x >> 6, lane = threadIdx.x & 63;
  if (lane == 0) { rdp[wave] = dp; rdn[wave] = dn; }
  __syncthreads();
  if (threadIdx.x == 0) {
    float DP = rdp[0] + rdp[1] + rdp[2] + rdp[3];
    float DN = rdn[0] + rdn[1] + rdn[2] + rdn[3];
    float na = norm[i];
    float cp = DP / fmaxf(na * norm[p], 1e-6f);
    float cn = DN / fmaxf(na * norm[n], 1e-6f);
    float loss = fmaxf(cp - cn + 0.1f, 0.0f);
    atomicAdd(out, loss * (1.0f / (float)NB));
  }
}

extern "C" void kernel_launch(void* const* d_in, const int* in_sizes, int n_in,
                              void* d_out, int out_size, void* d_ws, size_t ws_size,
                              hipStream_t stream) {
  const float* pred = (const float*)d_in[0]; // [8192,1024] f32
  const float* gt   = (const float*)d_in[1]; // [8192,14]  f32
  float* out = (float*)d_out;

  char* ws = (char*)d_ws;
  uint32_t* lbits = (uint32_t*)(ws);            // 32 KiB
  float*    norms = (float*)(ws + 32768);       // 32 KiB
  int*      posi  = (int*)(ws + 65536);         // 32 KiB
  int*      negi  = (int*)(ws + 98304);         // 32 KiB

  // JAX partitionable-threefry: key(42) = (0,42); split -> kp=T(key,(0,0)), kn=T(key,(0,1))
  uint32_t kp0, kp1, kn0, kn1;
  tf2x32_host(0u, 42u, 0u, 0u, &kp0, &kp1);
  tf2x32_host(0u, 42u, 0u, 1u, &kn0, &kn1);
  const uint32_t kps2 = kp0 ^ kp1 ^ 0x1BD11BDAu;
  const uint32_t kns2 = kn0 ^ kn1 ^ 0x1BD11BDAu;

  hipMemsetAsync(out, 0, sizeof(float), stream);
  k_norm<<<NB, 256, 0, stream>>>(pred, gt, norms, lbits);
  k_sample<<<NB, 256, 0, stream>>>(lbits, kp0, kp1, kps2, kn0, kn1, kns2, posi, negi);
  k_loss<<<NB, 256, 0, stream>>>(pred, norms, posi, negi, out);
}

// Round 5
// 242.047 us; speedup vs baseline: 1.3779x; 1.3779x over previous
//
#include <hip/hip_runtime.h>
#include <hip/hip_bf16.h>
#include <stdint.h>

#define NB 8192
#define ND 1024
#define NC 14

// rotl via single v_alignbit_b32: ((x:x) >> (32-r)) == rotl(x, r)
#define ROTL(x, r) __builtin_amdgcn_alignbit((x), (x), 32u - (r))
// guaranteed single-instruction x1 = x1 + s + imm (imm in 1..5 = inline const)
#define ADD3_IMM(x, s, imm) \
  asm("v_add3_u32 %0, %1, %2, " #imm : "=v"(x) : "v"(x), "v"(s))

// ---------------- host Threefry-2x32 (20 rounds), JAX-compatible ----------------
static inline uint32_t rotl32h(uint32_t x, int r) { return (x << r) | (x >> (32 - r)); }
static void tf2x32_host(uint32_t k0, uint32_t k1, uint32_t x0, uint32_t x1,
                        uint32_t* o0, uint32_t* o1) {
  uint32_t ks[3] = { k0, k1, k0 ^ k1 ^ 0x1BD11BDAu };
  static const int R[8] = {13, 15, 26, 6, 17, 29, 16, 24};
  x0 += k0; x1 += k1;
  for (int g = 0; g < 5; ++g) {
    const int* rr = (g & 1) ? (R + 4) : R;
    for (int i = 0; i < 4; ++i) { x0 += x1; x1 = rotl32h(x1, rr[i]); x1 ^= x0; }
    x0 += ks[(g + 1) % 3];
    x1 += ks[(g + 2) % 3] + (uint32_t)(g + 1);
  }
  *o0 = x0; *o1 = x1;
}

// ---------------- K1: row norms + label bitmasks (fused) ----------------
// lbits2[j] = labelmask | (bit14 if unlabeled); then for ANY anchor i:
//   isPos(i,j) == (lbits2[i] & lbits2[j]) != 0
__global__ void k_norm(const float* __restrict__ pred, const float* __restrict__ gt,
                       float* __restrict__ norm, uint32_t* __restrict__ lbits2) {
  const int row = blockIdx.x;
  const float4* p = (const float4*)(pred + (size_t)row * ND);
  float4 v = p[threadIdx.x];
  float s = v.x * v.x + v.y * v.y + v.z * v.z + v.w * v.w;
#pragma unroll
  for (int o = 32; o > 0; o >>= 1) s += __shfl_down(s, o, 64);
  __shared__ float red[4];
  const int wave = threadIdx.x >> 6, lane = threadIdx.x & 63;
  if (lane == 0) red[wave] = s;
  unsigned long long b =
      __ballot((int)threadIdx.x < NC && gt[row * NC + (int)threadIdx.x] != 0.0f);
  __syncthreads();
  if (threadIdx.x == 0) {
    uint32_t m = (uint32_t)(b & 0x3FFFull);
    lbits2[row] = m | ((m == 0u) ? 0x4000u : 0u);
    norm[row] = sqrtf(red[0] + red[1] + red[2] + red[3]);
  }
}

// ---------------- K2: gumbel-argmax sampling (the heavy kernel) ----------------
__global__ void __launch_bounds__(256) k_sample(
    const uint32_t* __restrict__ lbits2,
    uint32_t kp0, uint32_t kp1, uint32_t kps2,
    uint32_t kn0, uint32_t kn1, uint32_t kns2,
    int* __restrict__ pos_idx, int* __restrict__ neg_idx) {
  const uint32_t tid = threadIdx.x;
  const int i = blockIdx.x;
  const uint32_t bi = lbits2[i];
  const uint32_t fkp1 = kp1 + ((uint32_t)i << 13);  // K1 + fbase, folded
  const uint32_t fkn1 = kn1 + ((uint32_t)i << 13);

  uint32_t bkP = 0u, bjP = 0u, bkN = 0u, bjN = 0u;

#pragma unroll 8
  for (uint32_t k = 0; k < 32; ++k) {
    const uint32_t jv = tid + (k << 8);
    const uint32_t bj = lbits2[jv];
    const uint32_t m = bi & bj;          // != 0  <=>  positive
    const uint32_t s0 = m ? kp0 : kn0;   // 1 cmp feeds 4 cndmask
    const uint32_t s1 = m ? kp1 : kn1;
    const uint32_t s2 = m ? kps2 : kns2;
    const uint32_t f1 = m ? fkp1 : fkn1;
    uint32_t x0 = s0;
    uint32_t x1 = f1 + jv;               // = K1 + (fbase + j)
#define TFR(r) { x0 += x1; x1 = ROTL(x1, r); x1 ^= x0; }
    TFR(13) TFR(15) TFR(26) TFR(6)
    x0 += s1;  ADD3_IMM(x1, s2, 1);
    TFR(17) TFR(29) TFR(16) TFR(24)
    x0 += s2;  ADD3_IMM(x1, s0, 2);
    TFR(13) TFR(15) TFR(26) TFR(6)
    x0 += s0;  ADD3_IMM(x1, s1, 3);
    TFR(17) TFR(29) TFR(16) TFR(24)
    x0 += s1;  ADD3_IMM(x1, s2, 4);
    TFR(13) TFR(15) TFR(26) TFR(6)
    x0 += s2;  ADD3_IMM(x1, s0, 5);
#undef TFR
    // strict > keeps the first (smallest-j) occurrence within a thread,
    // matching jnp.argmax ties. key==0 never beating init is a ~2^-145000
    // event (needs ALL class keys zero) — accepted.
    const uint32_t key = (x0 ^ x1) >> 9;
    const bool pos = (m != 0u);
    const bool gtP = pos & (key > bkP);
    bkP = gtP ? key : bkP;
    bjP = gtP ? jv : bjP;
    const bool gtN = (!pos) & (key > bkN);
    bkN = gtN ? key : bkN;
    bjN = gtN ? jv : bjN;
  }

  // wave-level reduction with explicit (key, smaller-j) tie-break
#pragma unroll
  for (int off = 32; off > 0; off >>= 1) {
    uint32_t k2 = __shfl_down(bkP, off, 64), j2 = __shfl_down(bjP, off, 64);
    if (k2 > bkP || (k2 == bkP && j2 < bjP)) { bkP = k2; bjP = j2; }
    k2 = __shfl_down(bkN, off, 64); j2 = __shfl_down(bjN, off, 64);
    if (k2 > bkN || (k2 == bkN && j2 < bjN)) { bkN = k2; bjN = j2; }
  }
  __shared__ uint32_t sk[2][4], sj[2][4];
  const int wave = (int)tid >> 6, lane = (int)tid & 63;
  if (lane == 0) { sk[0][wave] = bkP; sj[0][wave] = bjP; sk[1][wave] = bkN; sj[1][wave] = bjN; }
  __syncthreads();
  if (tid == 0) {
    uint32_t bk = sk[0][0], bj = sj[0][0];
#pragma unroll
    for (int w = 1; w < 4; ++w)
      if (sk[0][w] > bk || (sk[0][w] == bk && sj[0][w] < bj)) { bk = sk[0][w]; bj = sj[0][w]; }
    pos_idx[i] = (int)bj;
    bk = sk[1][0]; bj = sj[1][0];
#pragma unroll
    for (int w = 1; w < 4; ++w)
      if (sk[1][w] > bk || (sk[1][w] == bk && sj[1][w] < bj)) { bk = sk[1][w]; bj = sj[1][w]; }
    neg_idx[i] = (int)bj;
  }
}

// ---------------- K3: per-row triplet cosine loss ----------------
__global__ void k_loss(const float* __restrict__ pred, const float* __restrict__ norm,
                       const int* __restrict__ pos_idx, const int* __restrict__ neg_idx,
                       float* __restrict__ losses) {
  const int i = blockIdx.x;
  const int p = pos_idx[i];
  const int n = neg_idx[i];
  const float4* A = (const float4*)(pred + (size_t)i * ND);
  const float4* P = (const float4*)(pred + (size_t)p * ND);
  const float4* Nn = (const float4*)(pred + (size_t)n * ND);
  float4 a = A[threadIdx.x], pp = P[threadIdx.x], nn = Nn[threadIdx.x];
  float dp = a.x * pp.x + a.y * pp.y + a.z * pp.z + a.w * pp.w;
  float dn = a.x * nn.x + a.y * nn.y + a.z * nn.z + a.w * nn.w;
#pragma unroll
  for (int o = 32; o > 0; o >>= 1) {
    dp += __shfl_down(dp, o, 64);
    dn += __shfl_down(dn, o, 64);
  }
  __shared__ float rdp[4], rdn[4];
  int wave = threadIdx.x >> 6, lane = threadIdx.x & 63;
  if (lane == 0) { rdp[wave] = dp; rdn[wave] = dn; }
  __syncthreads();
  if (threadIdx.x == 0) {
    float DP = rdp[0] + rdp[1] + rdp[2] + rdp[3];
    float DN = rdn[0] + rdn[1] + rdn[2] + rdn[3];
    float na = norm[i];
    float cp = DP / fmaxf(na * norm[p], 1e-6f);
    float cn = DN / fmaxf(na * norm[n], 1e-6f);
    losses[i] = fmaxf(cp - cn + 0.1f, 0.0f);
  }
}

// ---------------- K4: mean ----------------
__global__ void k_mean(const float* __restrict__ losses, float* __restrict__ out) {
  float s = 0.0f;
  for (int k = threadIdx.x; k < NB; k += 256) s += losses[k];
#pragma unroll
  for (int o = 32; o > 0; o >>= 1) s += __shfl_down(s, o, 64);
  __shared__ float red[4];
  int wave = threadIdx.x >> 6, lane = threadIdx.x & 63;
  if (lane == 0) red[wave] = s;
  __syncthreads();
  if (threadIdx.x == 0) out[0] = (red[0] + red[1] + red[2] + red[3]) / (float)NB;
}

extern "C" void kernel_launch(void* const* d_in, const int* in_sizes, int n_in,
                              void* d_out, int out_size, void* d_ws, size_t ws_size,
                              hipStream_t stream) {
  const float* pred = (const float*)d_in[0]; // [8192,1024] f32
  const float* gt   = (const float*)d_in[1]; // [8192,14]  f32
  float* out = (float*)d_out;

  char* ws = (char*)d_ws;
  uint32_t* lbits = (uint32_t*)(ws);            // 32 KiB
  float*    norms = (float*)(ws + 32768);       // 32 KiB
  int*      posi  = (int*)(ws + 65536);         // 32 KiB
  int*      negi  = (int*)(ws + 98304);         // 32 KiB
  float*    losses= (float*)(ws + 131072);      // 32 KiB

  // JAX partitionable-threefry: key(42) = (0,42); split -> kp=T(key,(0,0)), kn=T(key,(0,1))
  uint32_t kp0, kp1, kn0, kn1;
  tf2x32_host(0u, 42u, 0u, 0u, &kp0, &kp1);
  tf2x32_host(0u, 42u, 0u, 1u, &kn0, &kn1);
  const uint32_t kps2 = kp0 ^ kp1 ^ 0x1BD11BDAu;
  const uint32_t kns2 = kn0 ^ kn1 ^ 0x1BD11BDAu;

  k_norm<<<NB, 256, 0, stream>>>(pred, gt, norms, lbits);
  k_sample<<<NB, 256, 0, stream>>>(lbits, kp0, kp1, kps2, kn0, kn1, kns2, posi, negi);
  k_loss<<<NB, 256, 0, stream>>>(pred, norms, posi, negi, losses);
  k_mean<<<1, 256, 0, stream>>>(losses, out);
}

// Round 6
// 229.112 us; speedup vs baseline: 1.4557x; 1.0565x over previous
//
#include <hip/hip_runtime.h>
#include <hip/hip_bf16.h>
#include <stdint.h>

#define NB 8192
#define ND 1024
#define NC 14

// rotl via single v_alignbit_b32: ((x:x) >> (32-r)) == rotl(x, r)
#define ROTL(x, r) __builtin_amdgcn_alignbit((x), (x), 32u - (r))
// single-instruction x1 = x1 + s + imm (imm in 1..5 = inline const)
#define ADD3_IMM(x, s, imm) \
  asm("v_add3_u32 %0, %1, %2, " #imm : "=v"(x) : "v"(x), "v"(s))

// ---------------- host Threefry-2x32 (20 rounds), JAX-compatible ----------------
static inline uint32_t rotl32h(uint32_t x, int r) { return (x << r) | (x >> (32 - r)); }
static void tf2x32_host(uint32_t k0, uint32_t k1, uint32_t x0, uint32_t x1,
                        uint32_t* o0, uint32_t* o1) {
  uint32_t ks[3] = { k0, k1, k0 ^ k1 ^ 0x1BD11BDAu };
  static const int R[8] = {13, 15, 26, 6, 17, 29, 16, 24};
  x0 += k0; x1 += k1;
  for (int g = 0; g < 5; ++g) {
    const int* rr = (g & 1) ? (R + 4) : R;
    for (int i = 0; i < 4; ++i) { x0 += x1; x1 = rotl32h(x1, rr[i]); x1 ^= x0; }
    x0 += ks[(g + 1) % 3];
    x1 += ks[(g + 2) % 3] + (uint32_t)(g + 1);
  }
  *o0 = x0; *o1 = x1;
}

// ---------------- K1: label bitmasks ----------------
// lbits2[j] = labelmask | (bit14 if unlabeled); then for ANY anchor i:
//   isPos(i,j) == (lbits2[i] & lbits2[j]) != 0
__global__ void k_labels(const float* __restrict__ gt, uint32_t* __restrict__ lbits2) {
  const int i = blockIdx.x * 256 + threadIdx.x;
  uint32_t m = 0u;
#pragma unroll
  for (int c = 0; c < NC; ++c)
    m |= (gt[i * NC + c] != 0.0f) ? (1u << c) : 0u;
  lbits2[i] = m ? m : 0x4000u;
}

// ---------------- K2: gumbel-argmax sampling + fused triplet loss ----------------
__global__ void __launch_bounds__(256) k_fused(
    const uint32_t* __restrict__ lbits2, const float* __restrict__ pred,
    uint32_t kp0, uint32_t kp1, uint32_t kps2,
    uint32_t kn0, uint32_t kn1, uint32_t kns2,
    float* __restrict__ losses) {
  const uint32_t tid = threadIdx.x;
  const int i = blockIdx.x;
  const uint32_t bi = lbits2[i];
  // K1 + fbase + tid, folded per class (fbase = i*8192)
  const uint32_t ftP = kp1 + ((uint32_t)i << 13) + tid;
  const uint32_t ftN = kn1 + ((uint32_t)i << 13) + tid;

  // packed best: (key23 << 5) | (31-k)  -> max == (max key, then min k = min j)
  uint32_t bkP = 0u, bkN = 0u;

#pragma unroll 8
  for (uint32_t k = 0; k < 32; ++k) {
    const uint32_t bj = lbits2[tid + (k << 8)];
    const uint32_t m = bi & bj;          // != 0  <=>  positive
    const uint32_t s0 = m ? kp0 : kn0;   // 1 cmp feeds the cndmasks
    const uint32_t s1 = m ? kp1 : kn1;
    const uint32_t s2 = m ? kps2 : kns2;
    uint32_t x0 = s0;
    uint32_t x1 = (m ? ftP : ftN) + (k << 8);   // = K1 + (fbase + j)
#define TFR(r) { x0 += x1; x1 = ROTL(x1, r); x1 ^= x0; }
    TFR(13) TFR(15) TFR(26) TFR(6)
    x0 += s1;  ADD3_IMM(x1, s2, 1);
    TFR(17) TFR(29) TFR(16) TFR(24)
    x0 += s2;  ADD3_IMM(x1, s0, 2);
    TFR(13) TFR(15) TFR(26) TFR(6)
    x0 += s0;  ADD3_IMM(x1, s1, 3);
    TFR(17) TFR(29) TFR(16) TFR(24)
    x0 += s1;  ADD3_IMM(x1, s2, 4);
    TFR(13) TFR(15) TFR(26) TFR(6)
    x0 += s2;  ADD3_IMM(x1, s0, 5);
#undef TFR
    // key = top-23 uniform bits (monotone for gumbel-argmax); pack with
    // (31-k): max cand == max key, tie -> min k == min j within this thread.
    const uint32_t t = x0 ^ x1;
    const uint32_t cand = ((t >> 9) << 5) + (31u - k);  // lshl_add, 31-k is SALU
    const uint32_t selP = m ? cand : 0u;
    const uint32_t selN = cand ^ selP;                  // m ? 0 : cand
    bkP = bkP > selP ? bkP : selP;                      // v_max_u32
    bkN = bkN > selN ? bkN : selN;
  }

  // unpack to (key, j) and reduce with explicit (key desc, j asc) tie-break
  uint32_t keyP = bkP >> 5, jP = tid + ((31u - (bkP & 31u)) << 8);
  uint32_t keyN = bkN >> 5, jN = tid + ((31u - (bkN & 31u)) << 8);
#pragma unroll
  for (int off = 32; off > 0; off >>= 1) {
    uint32_t k2 = __shfl_down(keyP, off, 64), j2 = __shfl_down(jP, off, 64);
    if (k2 > keyP || (k2 == keyP && j2 < jP)) { keyP = k2; jP = j2; }
    k2 = __shfl_down(keyN, off, 64); j2 = __shfl_down(jN, off, 64);
    if (k2 > keyN || (k2 == keyN && j2 < jN)) { keyN = k2; jN = j2; }
  }
  __shared__ uint32_t sk[2][4], sj[2][4];
  __shared__ int spn[2];
  const int wave = (int)tid >> 6, lane = (int)tid & 63;
  if (lane == 0) { sk[0][wave] = keyP; sj[0][wave] = jP; sk[1][wave] = keyN; sj[1][wave] = jN; }
  __syncthreads();
  if (tid == 0) {
    uint32_t bk = sk[0][0], bj = sj[0][0];
#pragma unroll
    for (int w = 1; w < 4; ++w)
      if (sk[0][w] > bk || (sk[0][w] == bk && sj[0][w] < bj)) { bk = sk[0][w]; bj = sj[0][w]; }
    spn[0] = (int)bj;
    bk = sk[1][0]; bj = sj[1][0];
#pragma unroll
    for (int w = 1; w < 4; ++w)
      if (sk[1][w] > bk || (sk[1][w] == bk && sj[1][w] < bj)) { bk = sk[1][w]; bj = sj[1][w]; }
    spn[1] = (int)bj;
  }
  __syncthreads();

  // ---- fused loss for row i: cos(a,p) - cos(a,n) + margin, clamped ----
  const int p = spn[0], n = spn[1];
  const float4* A  = (const float4*)(pred + (size_t)i * ND);
  const float4* P  = (const float4*)(pred + (size_t)p * ND);
  const float4* Nv = (const float4*)(pred + (size_t)n * ND);
  float4 a = A[tid], pv = P[tid], nv = Nv[tid];
  float na = a.x * a.x + a.y * a.y + a.z * a.z + a.w * a.w;
  float np = pv.x * pv.x + pv.y * pv.y + pv.z * pv.z + pv.w * pv.w;
  float nn = nv.x * nv.x + nv.y * nv.y + nv.z * nv.z + nv.w * nv.w;
  float dp = a.x * pv.x + a.y * pv.y + a.z * pv.z + a.w * pv.w;
  float dn = a.x * nv.x + a.y * nv.y + a.z * nv.z + a.w * nv.w;
#pragma unroll
  for (int o = 32; o > 0; o >>= 1) {
    na += __shfl_down(na, o, 64);
    np += __shfl_down(np, o, 64);
    nn += __shfl_down(nn, o, 64);
    dp += __shfl_down(dp, o, 64);
    dn += __shfl_down(dn, o, 64);
  }
  __shared__ float red[4][5];
  if (lane == 0) { red[wave][0] = na; red[wave][1] = np; red[wave][2] = nn;
                   red[wave][3] = dp; red[wave][4] = dn; }
  __syncthreads();
  if (tid == 0) {
    float NA = red[0][0] + red[1][0] + red[2][0] + red[3][0];
    float NP = red[0][1] + red[1][1] + red[2][1] + red[3][1];
    float NN = red[0][2] + red[1][2] + red[2][2] + red[3][2];
    float DP = red[0][3] + red[1][3] + red[2][3] + red[3][3];
    float DN = red[0][4] + red[1][4] + red[2][4] + red[3][4];
    NA = sqrtf(NA); NP = sqrtf(NP); NN = sqrtf(NN);
    float cp = DP / fmaxf(NA * NP, 1e-6f);
    float cn = DN / fmaxf(NA * NN, 1e-6f);
    losses[i] = fmaxf(cp - cn + 0.1f, 0.0f);
  }
}

// ---------------- K3: mean ----------------
__global__ void k_mean(const float* __restrict__ losses, float* __restrict__ out) {
  float s = 0.0f;
  for (int k = threadIdx.x; k < NB; k += 256) s += losses[k];
#pragma unroll
  for (int o = 32; o > 0; o >>= 1) s += __shfl_down(s, o, 64);
  __shared__ float red[4];
  int wave = threadIdx.x >> 6, lane = threadIdx.x & 63;
  if (lane == 0) red[wave] = s;
  __syncthreads();
  if (threadIdx.x == 0) out[0] = (red[0] + red[1] + red[2] + red[3]) / (float)NB;
}

extern "C" void kernel_launch(void* const* d_in, const int* in_sizes, int n_in,
                              void* d_out, int out_size, void* d_ws, size_t ws_size,
                              hipStream_t stream) {
  const float* pred = (const float*)d_in[0]; // [8192,1024] f32
  const float* gt   = (const float*)d_in[1]; // [8192,14]  f32
  float* out = (float*)d_out;

  char* ws = (char*)d_ws;
  uint32_t* lbits  = (uint32_t*)(ws);        // 32 KiB
  float*    losses = (float*)(ws + 32768);   // 32 KiB

  // JAX partitionable-threefry: key(42) = (0,42); split -> kp=T(key,(0,0)), kn=T(key,(0,1))
  uint32_t kp0, kp1, kn0, kn1;
  tf2x32_host(0u, 42u, 0u, 0u, &kp0, &kp1);
  tf2x32_host(0u, 42u, 0u, 1u, &kn0, &kn1);
  const uint32_t kps2 = kp0 ^ kp1 ^ 0x1BD11BDAu;
  const uint32_t kns2 = kn0 ^ kn1 ^ 0x1BD11BDAu;

  k_labels<<<NB / 256, 256, 0, stream>>>(gt, lbits);
  k_fused<<<NB, 256, 0, stream>>>(lbits, pred, kp0, kp1, kps2, kn0, kn1, kns2, losses);
  k_mean<<<1, 256, 0, stream>>>(losses, out);
}

// Round 7
// 228.671 us; speedup vs baseline: 1.4585x; 1.0019x over previous
//
#include <hip/hip_runtime.h>
#include <hip/hip_bf16.h>
#include <stdint.h>

#define NB 8192
#define ND 1024
#define NC 14

// rotl via single v_alignbit_b32: ((x:x) >> (32-r)) == rotl(x, r)
#define ROTL(x, r) __builtin_amdgcn_alignbit((x), (x), 32u - (r))
// single-instruction x1 = x1 + s + imm (imm in 1..5 = inline const)
#define ADD3_IMM(x, s, imm) \
  asm("v_add3_u32 %0, %1, %2, " #imm : "=v"(x) : "v"(x), "v"(s))

// ---------------- host Threefry-2x32 (20 rounds), JAX-compatible ----------------
static inline uint32_t rotl32h(uint32_t x, int r) { return (x << r) | (x >> (32 - r)); }
static void tf2x32_host(uint32_t k0, uint32_t k1, uint32_t x0, uint32_t x1,
                        uint32_t* o0, uint32_t* o1) {
  uint32_t ks[3] = { k0, k1, k0 ^ k1 ^ 0x1BD11BDAu };
  static const int R[8] = {13, 15, 26, 6, 17, 29, 16, 24};
  x0 += k0; x1 += k1;
  for (int g = 0; g < 5; ++g) {
    const int* rr = (g & 1) ? (R + 4) : R;
    for (int i = 0; i < 4; ++i) { x0 += x1; x1 = rotl32h(x1, rr[i]); x1 ^= x0; }
    x0 += ks[(g + 1) % 3];
    x1 += ks[(g + 2) % 3] + (uint32_t)(g + 1);
  }
  *o0 = x0; *o1 = x1;
}

// ---------------- K1: label bitmasks, one thread per ROW-PAIR ----------------
// 2 rows = 28 floats = 7 aligned float4 loads; uint2 store.
// lbits2[j] = labelmask | (bit14 if unlabeled); then for ANY anchor i:
//   isPos(i,j) == (lbits2[i] & lbits2[j]) != 0
__global__ void k_labels(const float* __restrict__ gt, uint32_t* __restrict__ lbits2) {
  const int t = blockIdx.x * 64 + threadIdx.x;       // 4096 row-pairs
  const float4* g = (const float4*)(gt + (size_t)t * 28);
  float f[28];
  float4* fp = (float4*)f;
#pragma unroll
  for (int q = 0; q < 7; ++q) fp[q] = g[q];
  uint32_t m0 = 0u, m1 = 0u;
#pragma unroll
  for (int c = 0; c < NC; ++c) {
    m0 |= (f[c] != 0.0f) ? (1u << c) : 0u;
    m1 |= (f[NC + c] != 0.0f) ? (1u << c) : 0u;
  }
  uint2 r;
  r.x = m0 ? m0 : 0x4000u;
  r.y = m1 ? m1 : 0x4000u;
  ((uint2*)lbits2)[t] = r;
}

// ---------------- K2: gumbel-argmax sampling + fused triplet loss ----------------
__global__ void __launch_bounds__(256, 8) k_fused(
    const uint32_t* __restrict__ lbits2, const float* __restrict__ pred,
    uint32_t kp0, uint32_t kp1, uint32_t kps2,
    uint32_t kn0, uint32_t kn1, uint32_t kns2,
    float* __restrict__ losses) {
  const uint32_t tid = threadIdx.x;
  const int i = blockIdx.x;
  const uint32_t bi = lbits2[i];
  // K1 + fbase + tid, folded per class (fbase = i*8192)
  const uint32_t ftP = kp1 + ((uint32_t)i << 13) + tid;
  const uint32_t ftN = kn1 + ((uint32_t)i << 13) + tid;

  // packed best: (key23 << 5) | (31-k)  -> max == (max key, then min k = min j)
  uint32_t bkP = 0u, bkN = 0u;

#pragma unroll 8
  for (uint32_t k = 0; k < 32; ++k) {
    const uint32_t bj = lbits2[tid + (k << 8)];
    const uint32_t m = bi & bj;          // != 0  <=>  positive
    const uint32_t s0 = m ? kp0 : kn0;   // 1 cmp feeds the cndmasks
    const uint32_t s1 = m ? kp1 : kn1;
    const uint32_t s2 = m ? kps2 : kns2;
    uint32_t x0 = s0;
    uint32_t x1 = (m ? ftP : ftN) + (k << 8);   // = K1 + (fbase + j)
#define TFR(r) { x0 += x1; x1 = ROTL(x1, r); x1 ^= x0; }
    TFR(13) TFR(15) TFR(26) TFR(6)
    x0 += s1;  ADD3_IMM(x1, s2, 1);
    TFR(17) TFR(29) TFR(16) TFR(24)
    x0 += s2;  ADD3_IMM(x1, s0, 2);
    TFR(13) TFR(15) TFR(26) TFR(6)
    x0 += s0;  ADD3_IMM(x1, s1, 3);
    TFR(17) TFR(29) TFR(16) TFR(24)
    x0 += s1;  ADD3_IMM(x1, s2, 4);
    TFR(13) TFR(15) TFR(26) TFR(6)
    x0 += s2;  ADD3_IMM(x1, s0, 5);
#undef TFR
    // key = top-23 uniform bits (monotone for gumbel-argmax); pack with
    // (31-k): max cand == max key, tie -> min k == min j within this thread.
    const uint32_t t = x0 ^ x1;
    const uint32_t cand = ((t >> 9) << 5) + (31u - k);  // lshl_add, 31-k is SALU
    const uint32_t selP = m ? cand : 0u;
    const uint32_t selN = cand ^ selP;                  // m ? 0 : cand
    bkP = bkP > selP ? bkP : selP;                      // v_max_u32
    bkN = bkN > selN ? bkN : selN;
  }

  // unpack to (key, j) and reduce with explicit (key desc, j asc) tie-break
  uint32_t keyP = bkP >> 5, jP = tid + ((31u - (bkP & 31u)) << 8);
  uint32_t keyN = bkN >> 5, jN = tid + ((31u - (bkN & 31u)) << 8);
#pragma unroll
  for (int off = 32; off > 0; off >>= 1) {
    uint32_t k2 = __shfl_down(keyP, off, 64), j2 = __shfl_down(jP, off, 64);
    if (k2 > keyP || (k2 == keyP && j2 < jP)) { keyP = k2; jP = j2; }
    k2 = __shfl_down(keyN, off, 64); j2 = __shfl_down(jN, off, 64);
    if (k2 > keyN || (k2 == keyN && j2 < jN)) { keyN = k2; jN = j2; }
  }
  __shared__ uint32_t sk[2][4], sj[2][4];
  __shared__ int spn[2];
  const int wave = (int)tid >> 6, lane = (int)tid & 63;
  if (lane == 0) { sk[0][wave] = keyP; sj[0][wave] = jP; sk[1][wave] = keyN; sj[1][wave] = jN; }
  __syncthreads();
  if (tid == 0) {
    uint32_t bk = sk[0][0], bj = sj[0][0];
#pragma unroll
    for (int w = 1; w < 4; ++w)
      if (sk[0][w] > bk || (sk[0][w] == bk && sj[0][w] < bj)) { bk = sk[0][w]; bj = sj[0][w]; }
    spn[0] = (int)bj;
    bk = sk[1][0]; bj = sj[1][0];
#pragma unroll
    for (int w = 1; w < 4; ++w)
      if (sk[1][w] > bk || (sk[1][w] == bk && sj[1][w] < bj)) { bk = sk[1][w]; bj = sj[1][w]; }
    spn[1] = (int)bj;
  }
  __syncthreads();

  // ---- fused loss for row i: cos(a,p) - cos(a,n) + margin, clamped ----
  const int p = spn[0], n = spn[1];
  const float4* A  = (const float4*)(pred + (size_t)i * ND);
  const float4* P  = (const float4*)(pred + (size_t)p * ND);
  const float4* Nv = (const float4*)(pred + (size_t)n * ND);
  float4 a = A[tid], pv = P[tid], nv = Nv[tid];
  float na = a.x * a.x + a.y * a.y + a.z * a.z + a.w * a.w;
  float np = pv.x * pv.x + pv.y * pv.y + pv.z * pv.z + pv.w * pv.w;
  float nn = nv.x * nv.x + nv.y * nv.y + nv.z * nv.z + nv.w * nv.w;
  float dp = a.x * pv.x + a.y * pv.y + a.z * pv.z + a.w * pv.w;
  float dn = a.x * nv.x + a.y * nv.y + a.z * nv.z + a.w * nv.w;
#pragma unroll
  for (int o = 32; o > 0; o >>= 1) {
    na += __shfl_down(na, o, 64);
    np += __shfl_down(np, o, 64);
    nn += __shfl_down(nn, o, 64);
    dp += __shfl_down(dp, o, 64);
    dn += __shfl_down(dn, o, 64);
  }
  __shared__ float red[4][5];
  if (lane == 0) { red[wave][0] = na; red[wave][1] = np; red[wave][2] = nn;
                   red[wave][3] = dp; red[wave][4] = dn; }
  __syncthreads();
  if (tid == 0) {
    float NA = red[0][0] + red[1][0] + red[2][0] + red[3][0];
    float NP = red[0][1] + red[1][1] + red[2][1] + red[3][1];
    float NN = red[0][2] + red[1][2] + red[2][2] + red[3][2];
    float DP = red[0][3] + red[1][3] + red[2][3] + red[3][3];
    float DN = red[0][4] + red[1][4] + red[2][4] + red[3][4];
    NA = sqrtf(NA); NP = sqrtf(NP); NN = sqrtf(NN);
    float cp = DP / fmaxf(NA * NP, 1e-6f);
    float cn = DN / fmaxf(NA * NN, 1e-6f);
    losses[i] = fmaxf(cp - cn + 0.1f, 0.0f);
  }
}

// ---------------- K3: mean ----------------
__global__ void k_mean(const float* __restrict__ losses, float* __restrict__ out) {
  float s = 0.0f;
  for (int k = threadIdx.x; k < NB; k += 256) s += losses[k];
#pragma unroll
  for (int o = 32; o > 0; o >>= 1) s += __shfl_down(s, o, 64);
  __shared__ float red[4];
  int wave = threadIdx.x >> 6, lane = threadIdx.x & 63;
  if (lane == 0) red[wave] = s;
  __syncthreads();
  if (threadIdx.x == 0) out[0] = (red[0] + red[1] + red[2] + red[3]) / (float)NB;
}

extern "C" void kernel_launch(void* const* d_in, const int* in_sizes, int n_in,
                              void* d_out, int out_size, void* d_ws, size_t ws_size,
                              hipStream_t stream) {
  const float* pred = (const float*)d_in[0]; // [8192,1024] f32
  const float* gt   = (const float*)d_in[1]; // [8192,14]  f32
  float* out = (float*)d_out;

  char* ws = (char*)d_ws;
  uint32_t* lbits  = (uint32_t*)(ws);        // 32 KiB
  float*    losses = (float*)(ws + 32768);   // 32 KiB

  // JAX partitionable-threefry: key(42) = (0,42); split -> kp=T(key,(0,0)), kn=T(key,(0,1))
  uint32_t kp0, kp1, kn0, kn1;
  tf2x32_host(0u, 42u, 0u, 0u, &kp0, &kp1);
  tf2x32_host(0u, 42u, 0u, 1u, &kn0, &kn1);
  const uint32_t kps2 = kp0 ^ kp1 ^ 0x1BD11BDAu;
  const uint32_t kns2 = kn0 ^ kn1 ^ 0x1BD11BDAu;

  k_labels<<<NB / 128, 64, 0, stream>>>(gt, lbits);
  k_fused<<<NB, 256, 0, stream>>>(lbits, pred, kp0, kp1, kps2, kn0, kn1, kns2, losses);
  k_mean<<<1, 256, 0, stream>>>(losses, out);
}